// Round 8
// baseline (1461.933 us; speedup 1.0000x reference)
//
#include <hip/hip_runtime.h>
#include <hip/hip_fp16.h>

#define NFEAT 5
#define HID 64
#define BSH 9               // dst bucket = dst >> 9  (512 nodes/bucket)
#define BNODES 512
#define MAXBK 256           // max buckets (n <= 131072)
#define PSH 14              // src partition = src >> 14 (8 parts, n <= 131072)
#define NPART 8
#define CHUNK 4096          // edges per bin/hist block
#define IDXMASK 0xFFFFFF    // low 24 bits = src node id

__global__ void k_zero(int* p, int n) {
    int i = blockIdx.x * blockDim.x + threadIdx.x;
    if (i < n) p[i] = 0;
}

// ---- bucket histogram (dst>>9), LDS-merged ----
__global__ __launch_bounds__(256) void
k_bhist(const int* __restrict__ dst, int* bhist, int E) {
    __shared__ int h[MAXBK];
    int t = threadIdx.x;
    h[t] = 0;
    __syncthreads();
    int i0 = blockIdx.x * CHUNK;
    int i1 = i0 + CHUNK; if (i1 > E) i1 = E;
    for (int i = i0 + t; i < i1; i += 256) atomicAdd(&h[dst[i] >> BSH], 1);
    __syncthreads();
    if (h[t]) atomicAdd(&bhist[t], h[t]);
}

// ---- scan 256 bucket counts -> bbase[257], bcur ----
__global__ void k_bscan(const int* __restrict__ bhist, int* bbase, int* bcur) {
    __shared__ int sh[MAXBK];
    int t = threadIdx.x;
    int v = bhist[t];
    sh[t] = v;
    __syncthreads();
    for (int off = 1; off < 256; off <<= 1) {
        int a = (t >= off) ? sh[t - off] : 0;
        __syncthreads();
        sh[t] += a;
        __syncthreads();
    }
    int excl = sh[t] - v;
    bbase[t] = excl;
    bcur[t]  = excl;
    if (t == 255) bbase[256] = sh[255];
}

// ---- bin edges by dst-bucket (bucket-contiguous runs in `binned`) ----
__global__ __launch_bounds__(256) void
k_bin(const int* __restrict__ src, const int* __restrict__ dst,
      int* bcur, int2* __restrict__ binned, int E) {
    __shared__ int2 stg[CHUNK];
    __shared__ int hist[MAXBK], base[MAXBK], gb[MAXBK];
    int t = threadIdx.x;
    int e0 = blockIdx.x * CHUNK;
    int cc = E - e0; if (cc > CHUNK) cc = CHUNK;
    hist[t] = 0;
    __syncthreads();
    int2 my[CHUNK / 256]; int mb[CHUNK / 256];
#pragma unroll
    for (int k = 0; k < CHUNK / 256; ++k) {
        int i = e0 + k * 256 + t;
        if (i < E) {
            my[k].x = src[i]; my[k].y = dst[i];
            mb[k] = my[k].y >> BSH;
            atomicAdd(&hist[mb[k]], 1);
        } else mb[k] = -1;
    }
    __syncthreads();
    int c = hist[t];
    base[t] = c;
    __syncthreads();
    for (int off = 1; off < 256; off <<= 1) {
        int a = (t >= off) ? base[t - off] : 0;
        __syncthreads();
        base[t] += a;
        __syncthreads();
    }
    int excl = base[t] - c;
    base[t] = excl;
    gb[t] = c ? atomicAdd(&bcur[t], c) : 0;
    hist[t] = 0;   // reuse as placement cursor
    __syncthreads();
#pragma unroll
    for (int k = 0; k < CHUNK / 256; ++k) {
        if (mb[k] >= 0) {
            int p = base[mb[k]] + atomicAdd(&hist[mb[k]], 1);
            stg[p] = my[k];
        }
    }
    __syncthreads();
#pragma unroll
    for (int k = 0; k < CHUNK / 256; ++k) {
        int p = k * 256 + t;
        if (p < cc) {
            int2 v = stg[p];
            int b = v.y >> BSH;
            binned[gb[b] + (p - base[b])] = v;
        }
    }
}

// ---- per-bucket LDS counting sort, bins = srcpart<<9 | local dst (partition-major):
//      emits csr (with group-offset packed in bits 24-26), rpS/lenS per node, dis ----
__global__ __launch_bounds__(256) void
k_sort(const int2* __restrict__ binned, const int* __restrict__ bbase,
       int* __restrict__ rpS, int* __restrict__ lenS,
       int* __restrict__ csr, float* __restrict__ dis, int n) {
    __shared__ int hist[NPART * BNODES];   // 4096
    __shared__ int cur[NPART * BNODES];
    __shared__ int tmp[256];
    int t = threadIdx.x, b = blockIdx.x;
    int e0 = bbase[b], e1 = bbase[b + 1];
    int v0 = b << BSH;
    int nv = n - v0; if (nv > BNODES) nv = BNODES;
#pragma unroll
    for (int k = 0; k < 16; ++k) hist[k * 256 + t] = 0;
    __syncthreads();
    for (int i = e0 + t; i < e1; i += 256) {
        int2 ed = binned[i];
        int bin = ((ed.x >> PSH) << BSH) | (ed.y - v0);   // partition-major
        atomicAdd(&hist[bin], 1);
    }
    __syncthreads();
    // degree -> dis
    for (int vl = t; vl < nv; vl += 256) {
        int d = 0;
#pragma unroll
        for (int p = 0; p < NPART; ++p) d += hist[(p << BSH) + vl];
        dis[v0 + vl] = rsqrtf((float)d + 1.0f);
    }
    // exclusive scan of 4096 bins (16 bins/thread + block scan)
    int s = 0, b0 = t * 16;
#pragma unroll
    for (int k = 0; k < 16; ++k) { cur[b0 + k] = s; s += hist[b0 + k]; }
    tmp[t] = s;
    __syncthreads();
    for (int off = 1; off < 256; off <<= 1) {
        int a = (t >= off) ? tmp[t - off] : 0;
        __syncthreads();
        tmp[t] += a;
        __syncthreads();
    }
    int add = e0 + tmp[t] - s;
#pragma unroll
    for (int k = 0; k < 16; ++k) cur[b0 + k] += add;
#pragma unroll
    for (int k = 0; k < 16; ++k) {
        int bin = b0 + k, p = bin >> BSH, vl = bin & (BNODES - 1);
        if (vl < nv) {
            rpS[p * n + v0 + vl]  = cur[bin];
            lenS[p * n + v0 + vl] = hist[bin];
        }
    }
    __syncthreads();
    for (int i = e0 + t; i < e1; i += 256) {
        int2 ed = binned[i];
        int vl = ed.y - v0;
        int bin = ((ed.x >> PSH) << BSH) | vl;
        int pos = atomicAdd(&cur[bin], 1);
        csr[pos] = ed.x | ((vl & 7) << 24);   // pack within-group-of-8 offset
    }
}

__global__ void k_xscale(const float* __restrict__ x, const float* __restrict__ dis,
                         float* __restrict__ xs, int n) {
    int i = blockIdx.x * blockDim.x + threadIdx.x;
    if (i >= n) return;
    float d = dis[i];
#pragma unroll
    for (int c = 0; c < NFEAT; ++c) xs[i * NFEAT + c] = d * x[i * NFEAT + c];
}

// ---- layer 1: wave/node, lane-strided over concatenated 8 sub-rows ----
__global__ __launch_bounds__(256) void
k_layer1(const int* __restrict__ rpS, const int* __restrict__ lenS,
         const int* __restrict__ csr, const float* __restrict__ xs,
         const float* __restrict__ dis, const float* __restrict__ W1,
         const float* __restrict__ b1, __half* __restrict__ g1h, int n) {
    int wave = (blockIdx.x * blockDim.x + threadIdx.x) >> 6;
    int lane = threadIdx.x & 63;
    if (wave >= n) return;
    int v = wave;
    int sA = 0, lA = 0;
    if (lane < NPART) { sA = rpS[lane * n + v]; lA = lenS[lane * n + v]; }
    int S0=__shfl(sA,0,64),S1=__shfl(sA,1,64),S2=__shfl(sA,2,64),S3=__shfl(sA,3,64),
        S4=__shfl(sA,4,64),S5=__shfl(sA,5,64),S6=__shfl(sA,6,64),S7=__shfl(sA,7,64);
    int L0=__shfl(lA,0,64),L1=__shfl(lA,1,64),L2=__shfl(lA,2,64),L3=__shfl(lA,3,64),
        L4=__shfl(lA,4,64),L5=__shfl(lA,5,64),L6=__shfl(lA,6,64);
    int P1=L0,P2=P1+L1,P3=P2+L2,P4=P3+L3,P5=P4+L4,P6=P5+L5,P7=P6+L6,P8=P7+__shfl(lA,7,64);
    float a0=0,a1=0,a2=0,a3=0,a4=0;
    for (int j = lane; j < P8; j += 64) {
        int st=S0, off=j;
        if (j>=P1){st=S1;off=j-P1;}
        if (j>=P2){st=S2;off=j-P2;}
        if (j>=P3){st=S3;off=j-P3;}
        if (j>=P4){st=S4;off=j-P4;}
        if (j>=P5){st=S5;off=j-P5;}
        if (j>=P6){st=S6;off=j-P6;}
        if (j>=P7){st=S7;off=j-P7;}
        int s = csr[st + off] & IDXMASK;
        const float* q = xs + (size_t)s * NFEAT;
        a0+=q[0]; a1+=q[1]; a2+=q[2]; a3+=q[3]; a4+=q[4];
    }
#pragma unroll
    for (int m = 32; m > 0; m >>= 1) {
        a0 += __shfl_xor(a0,m,64); a1 += __shfl_xor(a1,m,64);
        a2 += __shfl_xor(a2,m,64); a3 += __shfl_xor(a3,m,64);
        a4 += __shfl_xor(a4,m,64);
    }
    float dv = dis[v];
    const float* pv = xs + (size_t)v * NFEAT;
    a0 = dv*(a0+pv[0]); a1 = dv*(a1+pv[1]); a2 = dv*(a2+pv[2]);
    a3 = dv*(a3+pv[3]); a4 = dv*(a4+pv[4]);
    int c = lane;
    float h = b1[c] + a0*W1[c] + a1*W1[64+c] + a2*W1[128+c]
            + a3*W1[192+c] + a4*W1[256+c];
    g1h[(size_t)v * HID + c] = __float2half(dv * fmaxf(h, 0.0f));
}

// ---- layer 2+3: wave per 8-node group, partition sweep, LDS f32 atomic accumulate ----
__global__ __launch_bounds__(256) void
k_layer23(const int* __restrict__ rpS, const int* __restrict__ lenS,
          const int* __restrict__ csr, const __half* __restrict__ g1h,
          const float* __restrict__ dis, const float* __restrict__ W2,
          const float* __restrict__ b2, const float* __restrict__ W3,
          float* __restrict__ svs, int n, int ng) {
    __shared__ float W2s[HID * HID];
    __shared__ float accs[4][8 * HID];
    int t = threadIdx.x;
    for (int i = t; i < HID * HID; i += 256) W2s[i] = W2[i];
    int wv = t >> 6, lane = t & 63;
    int g = blockIdx.x * 4 + wv;
    bool active = (g < ng);
    float* acc = accs[wv];
    int v0 = g << 3;
    if (active) {
#pragma unroll
        for (int i = 0; i < 8; ++i) {
            int vi = v0 + i;
            acc[(i << 6) + lane] = (vi < n)
                ? __half2float(g1h[(size_t)vi * HID + lane]) : 0.f;  // self term
        }
        for (int p = 0; p < NPART; ++p) {
            int stv = 0, lnv = 0;
            if (lane < 8) {
                int vi = v0 + lane;
                if (vi < n) { stv = rpS[p * n + vi]; lnv = lenS[p * n + vi]; }
            }
            lnv += __shfl_xor(lnv, 1, 64);
            lnv += __shfl_xor(lnv, 2, 64);
            lnv += __shfl_xor(lnv, 4, 64);
            int st = __shfl(stv, 0, 64);
            int ln = __shfl(lnv, 0, 64);
            int j = 0;
            for (; j + 8 <= ln; j += 8) {
                int e0 = csr[st+j],   e1 = csr[st+j+1], e2 = csr[st+j+2], e3 = csr[st+j+3];
                int e4 = csr[st+j+4], e5 = csr[st+j+5], e6 = csr[st+j+6], e7 = csr[st+j+7];
                float f0 = __half2float(g1h[(size_t)(e0 & IDXMASK) * HID + lane]);
                float f1 = __half2float(g1h[(size_t)(e1 & IDXMASK) * HID + lane]);
                float f2 = __half2float(g1h[(size_t)(e2 & IDXMASK) * HID + lane]);
                float f3 = __half2float(g1h[(size_t)(e3 & IDXMASK) * HID + lane]);
                float f4 = __half2float(g1h[(size_t)(e4 & IDXMASK) * HID + lane]);
                float f5 = __half2float(g1h[(size_t)(e5 & IDXMASK) * HID + lane]);
                float f6 = __half2float(g1h[(size_t)(e6 & IDXMASK) * HID + lane]);
                float f7 = __half2float(g1h[(size_t)(e7 & IDXMASK) * HID + lane]);
                atomicAdd(&acc[((e0 >> 24) << 6) + lane], f0);
                atomicAdd(&acc[((e1 >> 24) << 6) + lane], f1);
                atomicAdd(&acc[((e2 >> 24) << 6) + lane], f2);
                atomicAdd(&acc[((e3 >> 24) << 6) + lane], f3);
                atomicAdd(&acc[((e4 >> 24) << 6) + lane], f4);
                atomicAdd(&acc[((e5 >> 24) << 6) + lane], f5);
                atomicAdd(&acc[((e6 >> 24) << 6) + lane], f6);
                atomicAdd(&acc[((e7 >> 24) << 6) + lane], f7);
            }
            for (; j < ln; ++j) {
                int e = csr[st + j];
                float f = __half2float(g1h[(size_t)(e & IDXMASK) * HID + lane]);
                atomicAdd(&acc[((e >> 24) << 6) + lane], f);
            }
        }
    }
    __syncthreads();   // W2s visible + own-wave LDS atomics drained
    if (!active) return;
    float bb = b2[lane], w3 = W3[lane];
#pragma unroll 1
    for (int i = 0; i < 8; ++i) {
        int vi = v0 + i;
        if (vi >= n) break;
        float dv = dis[vi];
        float a = acc[(i << 6) + lane] * dv;
        float o = bb;
#pragma unroll
        for (int k = 0; k < HID; ++k)
            o = fmaf(__shfl(a, k, 64), W2s[(k << 6) + lane], o);
        o = fmaxf(o, 0.0f);
        float val = o * w3;
#pragma unroll
        for (int m = 32; m > 0; m >>= 1) val += __shfl_xor(val, m, 64);
        if (lane == 0) svs[vi] = dv * val;   // pre-scaled for output gather
    }
}

// ---- output: wave/node scalar gather over concatenated 8 sub-rows ----
__global__ __launch_bounds__(256) void
k_out(const int* __restrict__ rpS, const int* __restrict__ lenS,
      const int* __restrict__ csr, const float* __restrict__ svs,
      const float* __restrict__ dis, const float* __restrict__ b3,
      float* __restrict__ out, int n) {
    int wave = (blockIdx.x * blockDim.x + threadIdx.x) >> 6;
    int lane = threadIdx.x & 63;
    if (wave >= n) return;
    int v = wave;
    int sA = 0, lA = 0;
    if (lane < NPART) { sA = rpS[lane * n + v]; lA = lenS[lane * n + v]; }
    int S0=__shfl(sA,0,64),S1=__shfl(sA,1,64),S2=__shfl(sA,2,64),S3=__shfl(sA,3,64),
        S4=__shfl(sA,4,64),S5=__shfl(sA,5,64),S6=__shfl(sA,6,64),S7=__shfl(sA,7,64);
    int L0=__shfl(lA,0,64),L1=__shfl(lA,1,64),L2=__shfl(lA,2,64),L3=__shfl(lA,3,64),
        L4=__shfl(lA,4,64),L5=__shfl(lA,5,64),L6=__shfl(lA,6,64);
    int P1=L0,P2=P1+L1,P3=P2+L2,P4=P3+L3,P5=P4+L4,P6=P5+L5,P7=P6+L6,P8=P7+__shfl(lA,7,64);
    float acc = 0.f;
    for (int j = lane; j < P8; j += 64) {
        int st=S0, off=j;
        if (j>=P1){st=S1;off=j-P1;}
        if (j>=P2){st=S2;off=j-P2;}
        if (j>=P3){st=S3;off=j-P3;}
        if (j>=P4){st=S4;off=j-P4;}
        if (j>=P5){st=S5;off=j-P5;}
        if (j>=P6){st=S6;off=j-P6;}
        if (j>=P7){st=S7;off=j-P7;}
        acc += svs[csr[st + off] & IDXMASK];
    }
#pragma unroll
    for (int m = 32; m > 0; m >>= 1) acc += __shfl_xor(acc, m, 64);
    if (lane == 0) out[v] = b3[0] + dis[v] * (acc + svs[v]);
}

extern "C" void kernel_launch(void* const* d_in, const int* in_sizes, int n_in,
                              void* d_out, int out_size, void* d_ws, size_t ws_size,
                              hipStream_t stream) {
    const float* x  = (const float*)d_in[0];
    const int*   ei = (const int*)d_in[1];
    const float* W1 = (const float*)d_in[2];
    const float* b1 = (const float*)d_in[3];
    const float* W2 = (const float*)d_in[4];
    const float* b2 = (const float*)d_in[5];
    const float* W3 = (const float*)d_in[6];
    const float* b3 = (const float*)d_in[7];
    float* out = (float*)d_out;

    const int n = out_size;           // 100000
    const int E = in_sizes[1] / 2;    // 3200000
    const int* src = ei;
    const int* dst = ei + E;

    // ws layout (int units):
    // bhist[256] bbase[257] pad bcur[256] | rpS[8n] lenS[8n] | dis[n] svs[n] | csr[E]
    // | binned[2E ints] (g1h aliases low 32n ints; xs in the tail above 32n)
    int*    bhist  = (int*)d_ws;
    int*    bbase  = bhist + 256;
    int*    bcur   = bhist + 520;
    int*    rpS    = bhist + 1024;
    int*    lenS   = rpS + (size_t)8 * n;
    float*  dis    = (float*)(lenS + (size_t)8 * n);
    float*  svs    = dis + n;
    int*    csr    = (int*)(svs + n);
    int2*   binned = (int2*)(csr + E);
    __half* g1h    = (__half*)binned;
    float*  xs     = (float*)binned + (size_t)32 * n;

    const int B = 256;
    const int nchunk = (E + CHUNK - 1) / CHUNK;
    const int nbk    = (n + BNODES - 1) / BNODES;
    const int gridW  = ((size_t)n * 64 + B - 1) / B;   // wave per node
    const int ng     = (n + 7) >> 3;                   // groups of 8 nodes
    const int grid23 = (ng + 3) / 4;                   // 4 waves (groups) per block

    k_zero   <<<1, 256, 0, stream>>>(bhist, 256);
    k_bhist  <<<nchunk, 256, 0, stream>>>(dst, bhist, E);
    k_bscan  <<<1, 256, 0, stream>>>(bhist, bbase, bcur);
    k_bin    <<<nchunk, 256, 0, stream>>>(src, dst, bcur, binned, E);
    k_sort   <<<nbk, 256, 0, stream>>>(binned, bbase, rpS, lenS, csr, dis, n);
    k_xscale <<<(n + B - 1) / B, B, 0, stream>>>(x, dis, xs, n);
    k_layer1 <<<gridW, B, 0, stream>>>(rpS, lenS, csr, xs, dis, W1, b1, g1h, n);
    k_layer23<<<grid23, B, 0, stream>>>(rpS, lenS, csr, g1h, dis, W2, b2, W3, svs, n, ng);
    k_out    <<<gridW, B, 0, stream>>>(rpS, lenS, csr, svs, dis, b3, out, n);
}

// Round 9
// 524.475 us; speedup vs baseline: 2.7874x; 2.7874x over previous
//
#include <hip/hip_runtime.h>
#include <hip/hip_fp16.h>

#define NFEAT 5
#define HID 64
#define BSH 9               // dst bucket = dst >> 9  (512 nodes/bucket)
#define BNODES 512
#define MAXBK 256           // max buckets (n <= 131072)
#define PSH 14              // src partition = src >> 14 (8 parts, n <= 131072)
#define NPART 8
#define CHUNK 4096          // edges per bin/hist block
#define IDXMASK 0xFFFFFF    // low 24 bits = src node id; bits 24-27 = dst&15

__global__ void k_zero(int* p, int n) {
    int i = blockIdx.x * blockDim.x + threadIdx.x;
    if (i < n) p[i] = 0;
}

// ---- bucket histogram (dst>>9), LDS-merged ----
__global__ __launch_bounds__(256) void
k_bhist(const int* __restrict__ dst, int* bhist, int E) {
    __shared__ int h[MAXBK];
    int t = threadIdx.x;
    h[t] = 0;
    __syncthreads();
    int i0 = blockIdx.x * CHUNK;
    int i1 = i0 + CHUNK; if (i1 > E) i1 = E;
    for (int i = i0 + t; i < i1; i += 256) atomicAdd(&h[dst[i] >> BSH], 1);
    __syncthreads();
    if (h[t]) atomicAdd(&bhist[t], h[t]);
}

// ---- scan 256 bucket counts -> bbase[257], bcur ----
__global__ void k_bscan(const int* __restrict__ bhist, int* bbase, int* bcur) {
    __shared__ int sh[MAXBK];
    int t = threadIdx.x;
    int v = bhist[t];
    sh[t] = v;
    __syncthreads();
    for (int off = 1; off < 256; off <<= 1) {
        int a = (t >= off) ? sh[t - off] : 0;
        __syncthreads();
        sh[t] += a;
        __syncthreads();
    }
    int excl = sh[t] - v;
    bbase[t] = excl;
    bcur[t]  = excl;
    if (t == 255) bbase[256] = sh[255];
}

// ---- bin edges by dst-bucket (bucket-contiguous runs in `binned`) ----
__global__ __launch_bounds__(256) void
k_bin(const int* __restrict__ src, const int* __restrict__ dst,
      int* bcur, int2* __restrict__ binned, int E) {
    __shared__ int2 stg[CHUNK];
    __shared__ int hist[MAXBK], base[MAXBK], gb[MAXBK];
    int t = threadIdx.x;
    int e0 = blockIdx.x * CHUNK;
    int cc = E - e0; if (cc > CHUNK) cc = CHUNK;
    hist[t] = 0;
    __syncthreads();
    int2 my[CHUNK / 256]; int mb[CHUNK / 256];
#pragma unroll
    for (int k = 0; k < CHUNK / 256; ++k) {
        int i = e0 + k * 256 + t;
        if (i < E) {
            my[k].x = src[i]; my[k].y = dst[i];
            mb[k] = my[k].y >> BSH;
            atomicAdd(&hist[mb[k]], 1);
        } else mb[k] = -1;
    }
    __syncthreads();
    int c = hist[t];
    base[t] = c;
    __syncthreads();
    for (int off = 1; off < 256; off <<= 1) {
        int a = (t >= off) ? base[t - off] : 0;
        __syncthreads();
        base[t] += a;
        __syncthreads();
    }
    int excl = base[t] - c;
    base[t] = excl;
    gb[t] = c ? atomicAdd(&bcur[t], c) : 0;
    hist[t] = 0;   // reuse as placement cursor
    __syncthreads();
#pragma unroll
    for (int k = 0; k < CHUNK / 256; ++k) {
        if (mb[k] >= 0) {
            int p = base[mb[k]] + atomicAdd(&hist[mb[k]], 1);
            stg[p] = my[k];
        }
    }
    __syncthreads();
#pragma unroll
    for (int k = 0; k < CHUNK / 256; ++k) {
        int p = k * 256 + t;
        if (p < cc) {
            int2 v = stg[p];
            int b = v.y >> BSH;
            binned[gb[b] + (p - base[b])] = v;
        }
    }
}

// ---- per-bucket LDS counting sort, bins = srcpart<<9 | local dst (partition-major):
//      emits csr (node's group-of-16 offset packed in bits 24-27), rpS/lenS, dis ----
__global__ __launch_bounds__(256) void
k_sort(const int2* __restrict__ binned, const int* __restrict__ bbase,
       int* __restrict__ rpS, int* __restrict__ lenS,
       int* __restrict__ csr, float* __restrict__ dis, int n) {
    __shared__ int hist[NPART * BNODES];   // 4096
    __shared__ int cur[NPART * BNODES];
    __shared__ int tmp[256];
    int t = threadIdx.x, b = blockIdx.x;
    int e0 = bbase[b], e1 = bbase[b + 1];
    int v0 = b << BSH;
    int nv = n - v0; if (nv > BNODES) nv = BNODES;
#pragma unroll
    for (int k = 0; k < 16; ++k) hist[k * 256 + t] = 0;
    __syncthreads();
    for (int i = e0 + t; i < e1; i += 256) {
        int2 ed = binned[i];
        int bin = ((ed.x >> PSH) << BSH) | (ed.y - v0);   // partition-major
        atomicAdd(&hist[bin], 1);
    }
    __syncthreads();
    // degree -> dis
    for (int vl = t; vl < nv; vl += 256) {
        int d = 0;
#pragma unroll
        for (int p = 0; p < NPART; ++p) d += hist[(p << BSH) + vl];
        dis[v0 + vl] = rsqrtf((float)d + 1.0f);
    }
    // exclusive scan of 4096 bins (16 bins/thread + block scan)
    int s = 0, b0 = t * 16;
#pragma unroll
    for (int k = 0; k < 16; ++k) { cur[b0 + k] = s; s += hist[b0 + k]; }
    tmp[t] = s;
    __syncthreads();
    for (int off = 1; off < 256; off <<= 1) {
        int a = (t >= off) ? tmp[t - off] : 0;
        __syncthreads();
        tmp[t] += a;
        __syncthreads();
    }
    int add = e0 + tmp[t] - s;
#pragma unroll
    for (int k = 0; k < 16; ++k) cur[b0 + k] += add;
#pragma unroll
    for (int k = 0; k < 16; ++k) {
        int bin = b0 + k, p = bin >> BSH, vl = bin & (BNODES - 1);
        if (vl < nv) {
            rpS[p * n + v0 + vl]  = cur[bin];
            lenS[p * n + v0 + vl] = hist[bin];
        }
    }
    __syncthreads();
    for (int i = e0 + t; i < e1; i += 256) {
        int2 ed = binned[i];
        int vl = ed.y - v0;
        int bin = ((ed.x >> PSH) << BSH) | vl;
        int pos = atomicAdd(&cur[bin], 1);
        csr[pos] = ed.x | ((ed.y & 15) << 24);   // pack group-of-16 offset
    }
}

__global__ void k_xscale(const float* __restrict__ x, const float* __restrict__ dis,
                         float* __restrict__ xs, int n) {
    int i = blockIdx.x * blockDim.x + threadIdx.x;
    if (i >= n) return;
    float d = dis[i];
#pragma unroll
    for (int c = 0; c < NFEAT; ++c) xs[i * NFEAT + c] = d * x[i * NFEAT + c];
}

// ---- layer 1: wave/node, lane-strided over concatenated 8 sub-rows ----
__global__ __launch_bounds__(256) void
k_layer1(const int* __restrict__ rpS, const int* __restrict__ lenS,
         const int* __restrict__ csr, const float* __restrict__ xs,
         const float* __restrict__ dis, const float* __restrict__ W1,
         const float* __restrict__ b1, __half* __restrict__ g1h, int n) {
    int wave = (blockIdx.x * blockDim.x + threadIdx.x) >> 6;
    int lane = threadIdx.x & 63;
    if (wave >= n) return;
    int v = wave;
    int sA = 0, lA = 0;
    if (lane < NPART) { sA = rpS[lane * n + v]; lA = lenS[lane * n + v]; }
    int S0=__shfl(sA,0,64),S1=__shfl(sA,1,64),S2=__shfl(sA,2,64),S3=__shfl(sA,3,64),
        S4=__shfl(sA,4,64),S5=__shfl(sA,5,64),S6=__shfl(sA,6,64),S7=__shfl(sA,7,64);
    int L0=__shfl(lA,0,64),L1=__shfl(lA,1,64),L2=__shfl(lA,2,64),L3=__shfl(lA,3,64),
        L4=__shfl(lA,4,64),L5=__shfl(lA,5,64),L6=__shfl(lA,6,64);
    int P1=L0,P2=P1+L1,P3=P2+L2,P4=P3+L3,P5=P4+L4,P6=P5+L5,P7=P6+L6,P8=P7+__shfl(lA,7,64);
    float a0=0,a1=0,a2=0,a3=0,a4=0;
    for (int j = lane; j < P8; j += 64) {
        int st=S0, off=j;
        if (j>=P1){st=S1;off=j-P1;}
        if (j>=P2){st=S2;off=j-P2;}
        if (j>=P3){st=S3;off=j-P3;}
        if (j>=P4){st=S4;off=j-P4;}
        if (j>=P5){st=S5;off=j-P5;}
        if (j>=P6){st=S6;off=j-P6;}
        if (j>=P7){st=S7;off=j-P7;}
        int s = csr[st + off] & IDXMASK;
        const float* q = xs + (size_t)s * NFEAT;
        a0+=q[0]; a1+=q[1]; a2+=q[2]; a3+=q[3]; a4+=q[4];
    }
#pragma unroll
    for (int m = 32; m > 0; m >>= 1) {
        a0 += __shfl_xor(a0,m,64); a1 += __shfl_xor(a1,m,64);
        a2 += __shfl_xor(a2,m,64); a3 += __shfl_xor(a3,m,64);
        a4 += __shfl_xor(a4,m,64);
    }
    float dv = dis[v];
    const float* pv = xs + (size_t)v * NFEAT;
    a0 = dv*(a0+pv[0]); a1 = dv*(a1+pv[1]); a2 = dv*(a2+pv[2]);
    a3 = dv*(a3+pv[3]); a4 = dv*(a4+pv[4]);
    int c = lane;
    float h = b1[c] + a0*W1[c] + a1*W1[64+c] + a2*W1[128+c]
            + a3*W1[192+c] + a4*W1[256+c];
    g1h[(size_t)v * HID + c] = __float2half(dv * fmaxf(h, 0.0f));
}

// ---- layer 2+3: wave per 16-node group, partition sweep, register segment-merge,
//      non-atomic wave-private LDS accumulator (nodes sorted within partition run) ----
#define STEP(ek, fk) {                                          \
    int vl_ = (ek) >> 24;                                       \
    if (vl_ != cur) {                                           \
        if (cur >= 0) acc[(cur << 6) + lane] += racc;           \
        cur = vl_; racc = (fk);                                 \
    } else racc += (fk);                                        \
}

__global__ __launch_bounds__(256) void
k_layer23(const int* __restrict__ rpS, const int* __restrict__ lenS,
          const int* __restrict__ csr, const __half* __restrict__ g1h,
          const float* __restrict__ dis, const float* __restrict__ W2,
          const float* __restrict__ b2, const float* __restrict__ W3,
          float* __restrict__ svs, int n, int ng) {
    __shared__ float W2s[HID * HID];        // 16 KB
    __shared__ float accs[4][16 * HID];     // 16 KB
    int t = threadIdx.x;
    for (int i = t; i < HID * HID; i += 256) W2s[i] = W2[i];
    int wv = t >> 6, lane = t & 63;
    int g = blockIdx.x * 4 + wv;
    bool active = (g < ng);
    float* acc = accs[wv];
    int v0 = g << 4;
    if (active) {
#pragma unroll
        for (int i = 0; i < 16; ++i) {
            int vi = v0 + i;
            acc[(i << 6) + lane] = (vi < n)
                ? __half2float(g1h[(size_t)vi * HID + lane]) : 0.f;  // self term
        }
        int cur = -1; float racc = 0.f;
        for (int p = 0; p < NPART; ++p) {
            int l16 = 0;
            if (lane < 16 && v0 + lane < n) l16 = lenS[p * n + v0 + lane];
            l16 += __shfl_xor(l16, 1, 64);
            l16 += __shfl_xor(l16, 2, 64);
            l16 += __shfl_xor(l16, 4, 64);
            l16 += __shfl_xor(l16, 8, 64);
            int ln = __shfl(l16, 0, 64);
            int st = rpS[p * n + v0];
            int j = 0;
            for (; j + 8 <= ln; j += 8) {
                int e0 = csr[st+j],   e1 = csr[st+j+1], e2 = csr[st+j+2], e3 = csr[st+j+3];
                int e4 = csr[st+j+4], e5 = csr[st+j+5], e6 = csr[st+j+6], e7 = csr[st+j+7];
                float f0 = __half2float(g1h[(size_t)(e0 & IDXMASK) * HID + lane]);
                float f1 = __half2float(g1h[(size_t)(e1 & IDXMASK) * HID + lane]);
                float f2 = __half2float(g1h[(size_t)(e2 & IDXMASK) * HID + lane]);
                float f3 = __half2float(g1h[(size_t)(e3 & IDXMASK) * HID + lane]);
                float f4 = __half2float(g1h[(size_t)(e4 & IDXMASK) * HID + lane]);
                float f5 = __half2float(g1h[(size_t)(e5 & IDXMASK) * HID + lane]);
                float f6 = __half2float(g1h[(size_t)(e6 & IDXMASK) * HID + lane]);
                float f7 = __half2float(g1h[(size_t)(e7 & IDXMASK) * HID + lane]);
                STEP(e0, f0) STEP(e1, f1) STEP(e2, f2) STEP(e3, f3)
                STEP(e4, f4) STEP(e5, f5) STEP(e6, f6) STEP(e7, f7)
            }
            for (; j < ln; ++j) {
                int e = csr[st + j];
                float f = __half2float(g1h[(size_t)(e & IDXMASK) * HID + lane]);
                STEP(e, f)
            }
        }
        if (cur >= 0) acc[(cur << 6) + lane] += racc;   // final flush
    }
    __syncthreads();   // W2s visible; own-wave LDS writes drained
    if (!active) return;
    float bb = b2[lane], w3 = W3[lane];
#pragma unroll 1
    for (int i = 0; i < 16; ++i) {
        int vi = v0 + i;
        if (vi >= n) break;
        float dv = dis[vi];
        float a = acc[(i << 6) + lane] * dv;
        float o = bb;
#pragma unroll
        for (int k = 0; k < HID; ++k)
            o = fmaf(__shfl(a, k, 64), W2s[(k << 6) + lane], o);
        o = fmaxf(o, 0.0f);
        float val = o * w3;
#pragma unroll
        for (int m = 32; m > 0; m >>= 1) val += __shfl_xor(val, m, 64);
        if (lane == 0) svs[vi] = dv * val;   // pre-scaled for output gather
    }
}

// ---- output: wave/node scalar gather over concatenated 8 sub-rows ----
__global__ __launch_bounds__(256) void
k_out(const int* __restrict__ rpS, const int* __restrict__ lenS,
      const int* __restrict__ csr, const float* __restrict__ svs,
      const float* __restrict__ dis, const float* __restrict__ b3,
      float* __restrict__ out, int n) {
    int wave = (blockIdx.x * blockDim.x + threadIdx.x) >> 6;
    int lane = threadIdx.x & 63;
    if (wave >= n) return;
    int v = wave;
    int sA = 0, lA = 0;
    if (lane < NPART) { sA = rpS[lane * n + v]; lA = lenS[lane * n + v]; }
    int S0=__shfl(sA,0,64),S1=__shfl(sA,1,64),S2=__shfl(sA,2,64),S3=__shfl(sA,3,64),
        S4=__shfl(sA,4,64),S5=__shfl(sA,5,64),S6=__shfl(sA,6,64),S7=__shfl(sA,7,64);
    int L0=__shfl(lA,0,64),L1=__shfl(lA,1,64),L2=__shfl(lA,2,64),L3=__shfl(lA,3,64),
        L4=__shfl(lA,4,64),L5=__shfl(lA,5,64),L6=__shfl(lA,6,64);
    int P1=L0,P2=P1+L1,P3=P2+L2,P4=P3+L3,P5=P4+L4,P6=P5+L5,P7=P6+L6,P8=P7+__shfl(lA,7,64);
    float acc = 0.f;
    for (int j = lane; j < P8; j += 64) {
        int st=S0, off=j;
        if (j>=P1){st=S1;off=j-P1;}
        if (j>=P2){st=S2;off=j-P2;}
        if (j>=P3){st=S3;off=j-P3;}
        if (j>=P4){st=S4;off=j-P4;}
        if (j>=P5){st=S5;off=j-P5;}
        if (j>=P6){st=S6;off=j-P6;}
        if (j>=P7){st=S7;off=j-P7;}
        acc += svs[csr[st + off] & IDXMASK];
    }
#pragma unroll
    for (int m = 32; m > 0; m >>= 1) acc += __shfl_xor(acc, m, 64);
    if (lane == 0) out[v] = b3[0] + dis[v] * (acc + svs[v]);
}

extern "C" void kernel_launch(void* const* d_in, const int* in_sizes, int n_in,
                              void* d_out, int out_size, void* d_ws, size_t ws_size,
                              hipStream_t stream) {
    const float* x  = (const float*)d_in[0];
    const int*   ei = (const int*)d_in[1];
    const float* W1 = (const float*)d_in[2];
    const float* b1 = (const float*)d_in[3];
    const float* W2 = (const float*)d_in[4];
    const float* b2 = (const float*)d_in[5];
    const float* W3 = (const float*)d_in[6];
    const float* b3 = (const float*)d_in[7];
    float* out = (float*)d_out;

    const int n = out_size;           // 100000
    const int E = in_sizes[1] / 2;    // 3200000
    const int* src = ei;
    const int* dst = ei + E;

    // ws layout (int units):
    // bhist[256] bbase[257] pad bcur[256] | rpS[8n] lenS[8n] | dis[n] svs[n] | csr[E]
    // | binned[2E ints] (g1h aliases low 32n ints; xs in the tail above 32n)
    int*    bhist  = (int*)d_ws;
    int*    bbase  = bhist + 256;
    int*    bcur   = bhist + 520;
    int*    rpS    = bhist + 1024;
    int*    lenS   = rpS + (size_t)8 * n;
    float*  dis    = (float*)(lenS + (size_t)8 * n);
    float*  svs    = dis + n;
    int*    csr    = (int*)(svs + n);
    int2*   binned = (int2*)(csr + E);
    __half* g1h    = (__half*)binned;
    float*  xs     = (float*)binned + (size_t)32 * n;

    const int B = 256;
    const int nchunk = (E + CHUNK - 1) / CHUNK;
    const int nbk    = (n + BNODES - 1) / BNODES;
    const int gridW  = ((size_t)n * 64 + B - 1) / B;   // wave per node
    const int ng     = (n + 15) >> 4;                  // groups of 16 nodes
    const int grid23 = (ng + 3) / 4;                   // 4 waves (groups) per block

    k_zero   <<<1, 256, 0, stream>>>(bhist, 256);
    k_bhist  <<<nchunk, 256, 0, stream>>>(dst, bhist, E);
    k_bscan  <<<1, 256, 0, stream>>>(bhist, bbase, bcur);
    k_bin    <<<nchunk, 256, 0, stream>>>(src, dst, bcur, binned, E);
    k_sort   <<<nbk, 256, 0, stream>>>(binned, bbase, rpS, lenS, csr, dis, n);
    k_xscale <<<(n + B - 1) / B, B, 0, stream>>>(x, dis, xs, n);
    k_layer1 <<<gridW, B, 0, stream>>>(rpS, lenS, csr, xs, dis, W1, b1, g1h, n);
    k_layer23<<<grid23, B, 0, stream>>>(rpS, lenS, csr, g1h, dis, W2, b2, W3, svs, n, ng);
    k_out    <<<gridW, B, 0, stream>>>(rpS, lenS, csr, svs, dis, b3, out, n);
}